// Round 9
// baseline (175.746 us; speedup 1.0000x reference)
//
#include <hip/hip_runtime.h>

#define NUM_USER   4096
#define NUM_ITEM   16384
#define NUM_HIDDEN 64
#define B_SZ       1024
#define L_SZ       50
#define NPAIR      (B_SZ * L_SZ)              // 51200
#define SEG_ITEMS  1024                       // cells per segment-strip
#define NSEG       (NUM_USER * 16)            // 65536 strips tile each output plane
#define CAP        64                         // bin capacity (realistic max ~30)
#define NBUCKET    1024                       // bucketed unique-cell counters
#define FILL_BLOCKS 2048                      // fat blocks: each owns 32 strips = 256 KB of output
#define SEGS_PER_BLOCK (NSEG / FILL_BLOCKS)   // 32
#define F4_PER_BLOCK (SEGS_PER_BLOCK * SEG_ITEMS / 4)  // 8192 float4 per plane per block

// Thread-per-pair: serial 64-element dot (embeds are cache-resident), then bin
// (key,val,rating) into the owning strip. key = (seq<<10)|item_low; max key
// == numpy C-order last write -> winner selection is order-independent.
__global__ void pair_bin_kernel(const int* __restrict__ idx_user,
                                const int* __restrict__ item_sets,
                                const float* __restrict__ rating_sets,
                                const float* __restrict__ embed_user,
                                const float* __restrict__ embed_item,
                                unsigned int* __restrict__ seg_count,
                                unsigned int* __restrict__ seg_key,
                                float* __restrict__ seg_val,
                                float* __restrict__ seg_rat) {
    const int p  = blockIdx.x * 256 + threadIdx.x;   // 200 blocks x 256 = 51200 exactly
    const int b  = p / L_SZ;
    const int u  = idx_user[b];
    const int it = item_sets[p];

    const float4* eu = (const float4*)(embed_user + (size_t)u  * NUM_HIDDEN);
    const float4* ei = (const float4*)(embed_item + (size_t)it * NUM_HIDDEN);
    float acc = 0.f;
    #pragma unroll 4
    for (int j = 0; j < NUM_HIDDEN / 4; ++j) {
        float4 a = eu[j], c = ei[j];
        acc += a.x * c.x + a.y * c.y + a.z * c.z + a.w * c.w;
    }

    const int seg = (u << 4) | (it >> 10);
    unsigned int slot = atomicAdd(&seg_count[seg], 1u);
    if (slot < CAP) {
        const int base = seg * CAP + (int)slot;
        seg_key[base] = ((unsigned int)p << 10) | (unsigned int)(it & (SEG_ITEMS - 1));
        seg_val[base] = acc;
        seg_rat[base] = rating_sets[p];
    }
}

// Fat fill + post-sync fixup: the zero stream has NO data dependencies (memset-
// shaped, R5-proven at ~6.9 TB/s); strip counts are pre-issued and consumed only
// after __syncthreads(). Threads 0..31 then inject their strip's (~0.8 avg)
// binned entries as scattered scalar stores into L2-hot lines, resolving numpy
// last-write-wins by max key (order-independent -> replay-deterministic).
__global__ __launch_bounds__(256) void fill_fix_kernel(
        const unsigned int* __restrict__ seg_count,
        const unsigned int* __restrict__ seg_key,
        const float* __restrict__ seg_val,
        const float* __restrict__ seg_rat,
        float4* __restrict__ pred4,
        float4* __restrict__ label4,
        float* __restrict__ pred_mask,
        float* __restrict__ label,
        unsigned int* __restrict__ ucount) {
    const int t   = threadIdx.x;
    const int blk = blockIdx.x;
    __shared__ unsigned int s_tot;

    // Pre-issue this block's strip counts (t<32); consumed only after the sync.
    unsigned int kc = 0;
    if (t < SEGS_PER_BLOCK) kc = seg_count[blk * SEGS_PER_BLOCK + t];
    if (t == 0) s_tot = 0;

    // Branchless zero streams: 32 iterations x (16B to pred + 16B to label).
    const size_t base4 = (size_t)blk * F4_PER_BLOCK + t;
    const float4 z = {0.f, 0.f, 0.f, 0.f};
    #pragma unroll 8
    for (int i = 0; i < F4_PER_BLOCK / 256; ++i) {
        pred4 [base4 + (size_t)i * 256] = z;
        label4[base4 + (size_t)i * 256] = z;
    }
    __syncthreads();   // drains stores; zeros visible before fixups

    // Fixups: thread t < 32 owns strip blk*32+t exclusively (no cross-block races).
    unsigned int nuniq = 0;
    if (t < SEGS_PER_BLOCK) {
        int k = (int)(kc > CAP ? CAP : kc);
        const int seg     = blk * SEGS_PER_BLOCK + t;
        const int base    = seg * CAP;
        const size_t cell0 = (size_t)seg * SEG_ITEMS;
        for (int i = 0; i < k; ++i) {
            const int keyi = (int)seg_key[base + i];        // < 2^26, sign-safe
            const int item = keyi & (SEG_ITEMS - 1);
            bool win = true;
            for (int j = 0; j < k; ++j) {
                const int keyj = (int)seg_key[base + j];
                if (((keyj ^ keyi) & (SEG_ITEMS - 1)) == 0 && keyj > keyi) win = false;
            }
            pred_mask[cell0 + item] = seg_val[base + i];    // dups carry identical v
            if (win) { label[cell0 + item] = seg_rat[base + i]; ++nuniq; }
        }
        if (nuniq) atomicAdd(&s_tot, nuniq);
    }
    __syncthreads();
    if (t == 0 && s_tot)
        atomicAdd(&ucount[blk & (NBUCKET - 1)], s_tot);     // <=2 adds/bucket
}

// One block: reduce the NBUCKET partial counts, emit sparsity scalar.
__global__ void sparsity_kernel(const unsigned int* __restrict__ ucount,
                                float* __restrict__ out) {
    __shared__ unsigned int warp_sum[4];
    const int t = threadIdx.x;            // 256 threads = 4 waves
    unsigned int s = 0;
    #pragma unroll
    for (int i = 0; i < NBUCKET / 256; ++i) s += ucount[t + i * 256];
    #pragma unroll
    for (int m = 32; m >= 1; m >>= 1) s += __shfl_xor(s, m, 64);
    if ((t & 63) == 0) warp_sum[t >> 6] = s;
    __syncthreads();
    if (t == 0) {
        unsigned int total = warp_sum[0] + warp_sum[1] + warp_sum[2] + warp_sum[3];
        out[0] = (float)((double)NUM_USER * (double)NUM_ITEM / (double)total);
    }
}

extern "C" void kernel_launch(void* const* d_in, const int* in_sizes, int n_in,
                              void* d_out, int out_size, void* d_ws, size_t ws_size,
                              hipStream_t stream) {
    const int*   idx_user    = (const int*)d_in[0];
    const int*   item_sets   = (const int*)d_in[1];
    const float* rating_sets = (const float*)d_in[2];
    const float* embed_user  = (const float*)d_in[3];
    const float* embed_item  = (const float*)d_in[4];

    float* pred_mask = (float*)d_out;
    float* label     = pred_mask + (size_t)NUM_USER * NUM_ITEM;
    float* sparsity  = label     + (size_t)NUM_USER * NUM_ITEM;

    // ws layout: [seg_count: NSEG u32][ucount: NBUCKET u32][key|val|rat: NSEG*CAP each]
    unsigned int* seg_count = (unsigned int*)d_ws;
    unsigned int* ucount    = seg_count + NSEG;
    unsigned int* seg_key   = ucount + NBUCKET;
    float*        seg_val   = (float*)(seg_key + (size_t)NSEG * CAP);
    float*        seg_rat   = seg_val + (size_t)NSEG * CAP;

    // Zero only the counters (266 KB); bin payload slots 0..count-1 are always
    // freshly stored before being read.
    hipMemsetAsync(d_ws, 0, (size_t)(NSEG + NBUCKET) * sizeof(int), stream);

    pair_bin_kernel<<<NPAIR / 256, 256, 0, stream>>>(idx_user, item_sets, rating_sets,
                                                     embed_user, embed_item,
                                                     seg_count, seg_key, seg_val, seg_rat);
    fill_fix_kernel<<<FILL_BLOCKS, 256, 0, stream>>>(seg_count, seg_key, seg_val, seg_rat,
                                                     (float4*)pred_mask, (float4*)label,
                                                     pred_mask, label, ucount);
    sparsity_kernel<<<1, 256, 0, stream>>>(ucount, sparsity);
}

// Round 12
// 153.405 us; speedup vs baseline: 1.1456x; 1.1456x over previous
//
#include <hip/hip_runtime.h>

#define NUM_USER   4096
#define NUM_ITEM   16384
#define NUM_HIDDEN 64
#define B_SZ       1024
#define L_SZ       50
#define NPAIR      (B_SZ * L_SZ)              // 51200
#define SEG_ITEMS  1024                       // cells per segment-strip
#define NSEG       (NUM_USER * 16)            // 65536 strips tile each output plane
#define CAP        64                         // bin capacity (realistic max ~8)
#define PAIR_BLOCKS 200                       // 200 x 256 = 51200 pair threads
#define FILL_BLOCKS 2048                      // each streams 256 KB contiguous
#define F4_TOTAL   (1u << 25)                 // 2^29 B / 16 = both planes in float4
#define F4_PER_BLOCK (F4_TOTAL / FILL_BLOCKS) // 16384
#define INJ_BLOCKS (NSEG / 256)               // 256 blocks, thread-per-segment

typedef float f32x4 __attribute__((ext_vector_type(4)));  // native vector: OK for nontemporal builtin

// One kernel, two disjoint jobs picked by block range (block-uniform branch):
//   blocks 0..199   : thread-per-pair dot product + bin into per-segment lists
//   blocks 200..2247: branchless nontemporal zero stream (memset-shaped, one
//                     contiguous f32x4 range spanning BOTH output planes)
// The two ranges touch disjoint memory -> no ordering needed; the scheduler
// overlaps the ~13us of pair compute under the ~95us write stream.
__global__ __launch_bounds__(256) void fill_bin_kernel(
        const int* __restrict__ idx_user,
        const int* __restrict__ item_sets,
        const float* __restrict__ rating_sets,
        const float* __restrict__ embed_user,
        const float* __restrict__ embed_item,
        unsigned int* __restrict__ seg_count,
        unsigned int* __restrict__ seg_key,
        float* __restrict__ seg_val,
        float* __restrict__ seg_rat,
        f32x4* __restrict__ out4) {
    const int blk = blockIdx.x;
    if (blk < PAIR_BLOCKS) {
        // ---- pair job: dot + bin. key=(seq<<10)|item_low; max key == numpy
        // C-order last write -> winner selection later is order-independent.
        const int p  = blk * 256 + threadIdx.x;
        const int b  = p / L_SZ;
        const int u  = idx_user[b];
        const int it = item_sets[p];

        const float4* eu = (const float4*)(embed_user + (size_t)u  * NUM_HIDDEN);
        const float4* ei = (const float4*)(embed_item + (size_t)it * NUM_HIDDEN);
        float acc = 0.f;
        #pragma unroll 4
        for (int j = 0; j < NUM_HIDDEN / 4; ++j) {
            float4 a = eu[j], c = ei[j];
            acc += a.x * c.x + a.y * c.y + a.z * c.z + a.w * c.w;
        }

        const int seg = (u << 4) | (it >> 10);
        unsigned int slot = atomicAdd(&seg_count[seg], 1u);
        if (slot < CAP) {
            const int base = seg * CAP + (int)slot;
            seg_key[base] = ((unsigned int)p << 10) | (unsigned int)(it & (SEG_ITEMS - 1));
            seg_val[base] = acc;
            seg_rat[base] = rating_sets[p];
        }
    } else {
        // ---- fill job: zero 256 KB, no loads, no branches, nontemporal.
        const size_t base4 = (size_t)(blk - PAIR_BLOCKS) * F4_PER_BLOCK + threadIdx.x;
        const f32x4 z = {0.f, 0.f, 0.f, 0.f};
        #pragma unroll 16
        for (int i = 0; i < F4_PER_BLOCK / 256; ++i)
            __builtin_nontemporal_store(z, &out4[base4 + (size_t)i * 256]);
    }
}

// Thread-per-segment injection over the zeroed planes + fused sparsity finalize.
// Each segment's bins are exclusive to one thread -> no races; last-write-wins
// by max key; pred duplicates carry bit-identical values.
__global__ __launch_bounds__(256) void inject_kernel(
        const unsigned int* __restrict__ seg_count,
        const unsigned int* __restrict__ seg_key,
        const float* __restrict__ seg_val,
        const float* __restrict__ seg_rat,
        float* __restrict__ pred_mask,
        float* __restrict__ label,
        float* __restrict__ sparsity,
        unsigned int* __restrict__ tot,
        unsigned int* __restrict__ done) {
    __shared__ unsigned int wsum[4];
    const int t   = threadIdx.x;
    const int seg = blockIdx.x * 256 + t;

    unsigned int kc = seg_count[seg];
    int k = (int)(kc > CAP ? CAP : kc);
    unsigned int nuniq = 0;
    const int base = seg * CAP;
    const size_t cell0 = (size_t)seg * SEG_ITEMS;
    for (int i = 0; i < k; ++i) {
        const int keyi = (int)seg_key[base + i];     // < 2^26, sign-safe
        const int item = keyi & (SEG_ITEMS - 1);
        bool win = true;
        for (int j = 0; j < k; ++j) {
            const int keyj = (int)seg_key[base + j];
            if (((keyj ^ keyi) & (SEG_ITEMS - 1)) == 0 && keyj > keyi) win = false;
        }
        pred_mask[cell0 + item] = seg_val[base + i];
        if (win) { label[cell0 + item] = seg_rat[base + i]; ++nuniq; }
    }

    // block-reduce unique count, then one atomic per block; last block finishes.
    #pragma unroll
    for (int m = 32; m >= 1; m >>= 1) nuniq += __shfl_xor(nuniq, m, 64);
    if ((t & 63) == 0) wsum[t >> 6] = nuniq;
    __syncthreads();
    if (t == 0) {
        unsigned int bsum = wsum[0] + wsum[1] + wsum[2] + wsum[3];
        atomicAdd(tot, bsum);
        __threadfence();
        unsigned int old = atomicAdd(done, 1u);
        if (old == (unsigned int)(gridDim.x - 1)) {
            __threadfence();
            unsigned int total = atomicAdd(tot, 0u);   // atomic read, all adds visible
            sparsity[0] = (float)((double)NUM_USER * (double)NUM_ITEM / (double)total);
        }
    }
}

extern "C" void kernel_launch(void* const* d_in, const int* in_sizes, int n_in,
                              void* d_out, int out_size, void* d_ws, size_t ws_size,
                              hipStream_t stream) {
    const int*   idx_user    = (const int*)d_in[0];
    const int*   item_sets   = (const int*)d_in[1];
    const float* rating_sets = (const float*)d_in[2];
    const float* embed_user  = (const float*)d_in[3];
    const float* embed_item  = (const float*)d_in[4];

    float* pred_mask = (float*)d_out;
    float* label     = pred_mask + (size_t)NUM_USER * NUM_ITEM;
    float* sparsity  = label     + (size_t)NUM_USER * NUM_ITEM;

    // ws layout: [seg_count: NSEG u32][tot][done][seg_key|seg_val|seg_rat: NSEG*CAP each]
    unsigned int* seg_count = (unsigned int*)d_ws;
    unsigned int* tot       = seg_count + NSEG;
    unsigned int* done      = tot + 1;
    unsigned int* seg_key   = done + 1;
    float*        seg_val   = (float*)(seg_key + (size_t)NSEG * CAP);
    float*        seg_rat   = seg_val + (size_t)NSEG * CAP;

    // Zero only counters (~262 KB); bin payload slots 0..count-1 are always
    // freshly stored before being read.
    hipMemsetAsync(d_ws, 0, (size_t)(NSEG + 2) * sizeof(int), stream);

    fill_bin_kernel<<<PAIR_BLOCKS + FILL_BLOCKS, 256, 0, stream>>>(
        idx_user, item_sets, rating_sets, embed_user, embed_item,
        seg_count, seg_key, seg_val, seg_rat, (f32x4*)d_out);
    inject_kernel<<<INJ_BLOCKS, 256, 0, stream>>>(
        seg_count, seg_key, seg_val, seg_rat,
        pred_mask, label, sparsity, tot, done);
}

// Round 13
// 131.433 us; speedup vs baseline: 1.3372x; 1.1672x over previous
//
#include <hip/hip_runtime.h>

#define NUM_USER   4096
#define NUM_ITEM   16384
#define NUM_HIDDEN 64
#define B_SZ       1024
#define L_SZ       50
#define NPAIR      (B_SZ * L_SZ)   // 51200
#define KROWS      64              // max batch rows tracked per user
#define NBUCKET    1024            // bucketed unique-cell counters (atomic spread)
#define WAVES_PER_BLOCK 8          // 512 threads -> 6400 scatter blocks (8x fewer dispatches)

// One block, 1024 threads: zero the counters (replaces a ws-memset node), then
// bucket batch rows by user (thread b owns row b). B_SZ == blockDim exactly.
__global__ __launch_bounds__(1024) void init_build_kernel(
        const int* __restrict__ idx_user,
        int* __restrict__ user_count,
        unsigned int* __restrict__ ucount,
        int* __restrict__ user_rows) {
    const int t = threadIdx.x;
    #pragma unroll
    for (int i = 0; i < NUM_USER / 1024; ++i) user_count[t + i * 1024] = 0;
    ucount[t] = 0;                               // NBUCKET == 1024
    __syncthreads();
    const int u = idx_user[t];
    const int slot = atomicAdd(&user_count[u], 1);
    if (slot < KROWS) user_rows[u * KROWS + slot] = t;
}

// R2-proven scatter, packed 8 waves/block: wave w handles pair p. Lane h holds
// hidden-dim h of the dot; lanes 0..49 check duplicate (u,item) pairs with
// LATER sequence number; per-wave ballot decides the numpy last-write winner
// (order-independent -> deterministic across graph replays).
__global__ __launch_bounds__(512) void scatter_kernel(
        const int* __restrict__ idx_user,
        const int* __restrict__ item_sets,
        const float* __restrict__ rating_sets,
        const float* __restrict__ embed_user,
        const float* __restrict__ embed_item,
        float* __restrict__ pred_mask,
        float* __restrict__ label,
        const int* __restrict__ user_count,
        const int* __restrict__ user_rows,
        unsigned int* __restrict__ ucount) {
    const int p    = blockIdx.x * WAVES_PER_BLOCK + (threadIdx.x >> 6);
    const int lane = threadIdx.x & 63;
    const int b    = p / L_SZ;
    const int l    = p - b * L_SZ;

    const int u  = idx_user[b];
    const int it = item_sets[p];

    // 64-wide dot product: lane h multiplies element h, butterfly reduce.
    float v = embed_user[u * NUM_HIDDEN + lane] * embed_item[it * NUM_HIDDEN + lane];
    #pragma unroll
    for (int m = 32; m >= 1; m >>= 1) v += __shfl_xor(v, m, 64);

    // Duplicate detection: any pair with larger seq (same row later l, or later
    // row of the same user) targeting the same item? Lanes 0..49 check one slot each.
    bool dup = false;
    if (lane > l && lane < L_SZ) dup = (item_sets[b * L_SZ + lane] == it);
    int cnt = user_count[u];
    if (cnt > KROWS) cnt = KROWS;
    for (int s = 0; s < cnt; ++s) {
        int b2 = user_rows[u * KROWS + s];
        if (b2 > b && lane < L_SZ) dup |= (item_sets[b2 * L_SZ + lane] == it);
    }
    unsigned long long anydup = __ballot(dup);   // wave-scoped: safe with 8 waves/block

    if (lane == 0) {
        size_t cell = (size_t)u * NUM_ITEM + it;
        // pred value identical for all duplicates of (u,it) -> unconditional store safe.
        pred_mask[cell] = v;
        if (anydup == 0ull) {
            label[cell] = rating_sets[p];                 // last writer in numpy order
            atomicAdd(&ucount[p & (NBUCKET - 1)], 1u);    // ~50 adds/bucket, spread
        }
    }
}

// One block: reduce the NBUCKET partial counts, emit sparsity scalar.
__global__ void sparsity_kernel(const unsigned int* __restrict__ ucount,
                                float* __restrict__ out) {
    __shared__ unsigned int warp_sum[4];
    const int t = threadIdx.x;            // 256 threads = 4 waves
    unsigned int s = 0;
    #pragma unroll
    for (int i = 0; i < NBUCKET / 256; ++i) s += ucount[t + i * 256];
    #pragma unroll
    for (int m = 32; m >= 1; m >>= 1) s += __shfl_xor(s, m, 64);
    if ((t & 63) == 0) warp_sum[t >> 6] = s;
    __syncthreads();
    if (t == 0) {
        unsigned int total = warp_sum[0] + warp_sum[1] + warp_sum[2] + warp_sum[3];
        out[0] = (float)((double)NUM_USER * (double)NUM_ITEM / (double)total);
    }
}

extern "C" void kernel_launch(void* const* d_in, const int* in_sizes, int n_in,
                              void* d_out, int out_size, void* d_ws, size_t ws_size,
                              hipStream_t stream) {
    const int*   idx_user    = (const int*)d_in[0];
    const int*   item_sets   = (const int*)d_in[1];
    const float* rating_sets = (const float*)d_in[2];
    const float* embed_user  = (const float*)d_in[3];
    const float* embed_item  = (const float*)d_in[4];

    float* pred_mask = (float*)d_out;
    float* label     = pred_mask + (size_t)NUM_USER * NUM_ITEM;
    float* sparsity  = label     + (size_t)NUM_USER * NUM_ITEM;

    // ws layout: [user_count: 4096][ucount: NBUCKET][user_rows: 4096*KROWS]
    int*          user_count = (int*)d_ws;
    unsigned int* ucount     = (unsigned int*)(user_count + NUM_USER);
    int*          user_rows  = (int*)(ucount + NBUCKET);

    // 4 graph nodes. The 537 MB zero uses the runtime's fill (measured 6.7-6.9
    // TB/s -- faster than any custom kernel fill we've benched); counters are
    // zeroed inside init_build (no ws-memset node).
    hipMemsetAsync(d_out, 0, (size_t)out_size * sizeof(float), stream);
    init_build_kernel<<<1, 1024, 0, stream>>>(idx_user, user_count, ucount, user_rows);
    scatter_kernel<<<NPAIR / WAVES_PER_BLOCK, 512, 0, stream>>>(
        idx_user, item_sets, rating_sets, embed_user, embed_item,
        pred_mask, label, user_count, user_rows, ucount);
    sparsity_kernel<<<1, 256, 0, stream>>>(ucount, sparsity);
}